// Round 14
// baseline (455.753 us; speedup 1.0000x reference)
//
#include <hip/hip_runtime.h>
#include <hip/hip_bf16.h>

// Problem constants
#define P 7
#define C_IN 512
#define C_MID 1024          // 2 * C_IN
#define C_CLS 1029          // P*P*21
#define C_BOX 4116          // P*P*21*4
#define FH 38
#define FW 50
#define NPIX 1900           // FH*FW
#define KROIS 300
#define COUT_SCORE 21
#define COUT_BOX 84
#define NPAIRS (KROIS * (COUT_SCORE + COUT_BOX))   // 31500

// Static device scratch. Fully overwritten every call; deterministic.
__device__ float g_feat2[C_MID * NPIX];   // 1024 x 1900
__device__ float g_score[C_CLS * NPIX];   // 1029 x 1900
__device__ float g_bbox [C_BOX * NPIX];   // 4116 x 1900

// ---------------------------------------------------------------------------
// GEMM + bias + relu (exact f32, R1 semantics — no quantization anywhere):
//   out[m,n] = relu( f32-accum sum_k W[m,k]*X[k,n] + bias[m] )
// 64x64 tile, 256 threads, 4x4 micro-tile, K-step 16, float4 staging.
// ---------------------------------------------------------------------------
__device__ __forceinline__ void gemm_body(
    const float* __restrict__ W, const float* __restrict__ X,
    const float* __restrict__ bias, float* __restrict__ out,
    int M, int K, int N)
{
    __shared__ float As[16][68];   // As[kk][m] (A transposed)
    __shared__ float Bs[16][68];   // Bs[kk][n]

    const int tid = threadIdx.x;
    const int bm = blockIdx.y * 64;
    const int bn = blockIdx.x * 64;
    const int tx = tid & 15;   // -> n
    const int ty = tid >> 4;   // -> m

    float acc[4][4] = {};

    const int am = tid >> 2;         // 0..63
    const int ak = (tid & 3) * 4;    // 0,4,8,12
    const int bk = tid >> 4;         // 0..15
    const int bnn = (tid & 15) * 4;  // 0..60

    for (int k0 = 0; k0 < K; k0 += 16) {   // K = 512/1024: multiple of 16
        float4 av;
        if (bm + am < M) {
            av = *reinterpret_cast<const float4*>(&W[(size_t)(bm + am) * K + (k0 + ak)]);
        } else {
            av = make_float4(0.f, 0.f, 0.f, 0.f);
        }
        As[ak + 0][am] = av.x;
        As[ak + 1][am] = av.y;
        As[ak + 2][am] = av.z;
        As[ak + 3][am] = av.w;

        float4 bv;
        const int col = bn + bnn;
        const float* xrow = &X[(size_t)(k0 + bk) * N];
        if (col + 3 < N) {
            bv = *reinterpret_cast<const float4*>(&xrow[col]);   // rows 16B aligned
        } else {
            bv.x = (col + 0 < N) ? xrow[col + 0] : 0.f;
            bv.y = (col + 1 < N) ? xrow[col + 1] : 0.f;
            bv.z = (col + 2 < N) ? xrow[col + 2] : 0.f;
            bv.w = (col + 3 < N) ? xrow[col + 3] : 0.f;
        }
        *reinterpret_cast<float4*>(&Bs[bk][bnn]) = bv;

        __syncthreads();

        #pragma unroll
        for (int kk = 0; kk < 16; ++kk) {
            float4 a = *reinterpret_cast<const float4*>(&As[kk][ty * 4]);
            float4 b = *reinterpret_cast<const float4*>(&Bs[kk][tx * 4]);
            float ar[4] = {a.x, a.y, a.z, a.w};
            float br[4] = {b.x, b.y, b.z, b.w};
            #pragma unroll
            for (int r = 0; r < 4; ++r)
                #pragma unroll
                for (int c = 0; c < 4; ++c)
                    acc[r][c] += ar[r] * br[c];
        }

        __syncthreads();
    }

    #pragma unroll
    for (int r = 0; r < 4; ++r) {
        const int m = bm + ty * 4 + r;
        if (m >= M) continue;
        const float bmv = bias[m];
        #pragma unroll
        for (int c = 0; c < 4; ++c) {
            const int n = bn + tx * 4 + c;
            if (n < N) out[(size_t)m * N + n] = fmaxf(acc[r][c] + bmv, 0.f);
        }
    }
}

__global__ __launch_bounds__(256) void gemm1_k(
    const float* __restrict__ W, const float* __restrict__ X,
    const float* __restrict__ b)
{
    gemm_body(W, X, b, g_feat2, C_MID, C_IN, NPIX);
}

__global__ __launch_bounds__(256) void gemm2_k(
    const float* __restrict__ W, const float* __restrict__ b)
{
    gemm_body(W, g_feat2, b, g_score, C_CLS, C_MID, NPIX);
}

__global__ __launch_bounds__(256) void gemm3_k(
    const float* __restrict__ W, const float* __restrict__ b)
{
    gemm_body(W, g_feat2, b, g_bbox, C_BOX, C_MID, NPIX);
}

// ---------------------------------------------------------------------------
// PS-ROI pool + bin-mean. One wave per (roi k, out channel c); lane l<49
// computes bin (i=l/7, j=l%7).
//
// ROUND-13 SEMANTICS PROBE (single variable vs strict-f32 R1):
//   bin_w = rn32( roi_w * rn32(1/7) )   [multiply-by-reciprocal]
// instead of
//   bin_w = rn32( roi_w / 7 )           [division]
// Rationale: the persistent 0.0234375 site is invariant under f32/f64/FMA
// BOUNDARY evaluation (R1=R2=R8 bit-identical) — and exact-integer sites
// are provably implementation-invariant — so the flip site must be a
// binw-ULP knife-edge: the oracle's bin_w itself differs by 1 ulp from the
// correctly-rounded quotient. rn(roi_w * rn(1/7)) is the canonical such
// arithmetic (compiler/port div->recip-mul rewrite; 1-ulp-different for
// ~30% of roi widths). f64 DIVISION (R2) targets the same real quotient
// -> same boundary side as f32 division, explaining the bit-identities;
// R5 (eval-widening) and R8 (FMA) only changed the SECOND rounding ->
// different sites. This is the last untested member of the family.
// Everything else is bit-identical to R1 (clipped cnt, mul-then-add RN).
// ---------------------------------------------------------------------------
__global__ __launch_bounds__(256) void psroi_pool_mean(
    const float* __restrict__ rois, float* __restrict__ out)
{
    __shared__ float red[4][64];
    const int wid = threadIdx.x >> 6;
    const int lane = threadIdx.x & 63;
    const int pair = blockIdx.x * 4 + wid;   // grid exact: pair < NPAIRS

    const int k = pair / (COUT_SCORE + COUT_BOX);
    const int c = pair % (COUT_SCORE + COUT_BOX);

    const float* maps;
    int cbase;
    float* outp;
    if (c < COUT_SCORE) {
        maps = g_score;
        cbase = c * (P * P);
        outp = out + (size_t)k * COUT_SCORE + c;
    } else {
        const int cb = c - COUT_SCORE;
        maps = g_bbox;
        cbase = cb * (P * P);
        outp = out + (size_t)KROIS * COUT_SCORE + (size_t)k * COUT_BOX + cb;
    }

    // rois layout: (ymin, xmin, ymax, xmax); reference permutes to xyxy.
    const float ymin = rois[k * 4 + 0];
    const float xmin = rois[k * 4 + 1];
    const float ymax = rois[k * 4 + 2];
    const float xmax = rois[k * 4 + 3];

    // Strict-f32 ROI prep (R1 semantics: mul-then-add, RN, no FMA),
    // EXCEPT bin_w/bin_h via multiply-by-reciprocal (the probe variable).
    const float x1 = __fmul_rn(rintf(xmin), 0.0625f);
    const float y1 = __fmul_rn(rintf(ymin), 0.0625f);
    const float x2 = __fmul_rn(__fadd_rn(rintf(xmax), 1.0f), 0.0625f);
    const float y2 = __fmul_rn(__fadd_rn(rintf(ymax), 1.0f), 0.0625f);
    const float roi_w = fmaxf(__fsub_rn(x2, x1), 0.1f);
    const float roi_h = fmaxf(__fsub_rn(y2, y1), 0.1f);
    const float inv7 = 1.0f / 7.0f;   // constant-folded rn32(1/7)
    const float bin_w = __fmul_rn(roi_w, inv7);
    const float bin_h = __fmul_rn(roi_h, inv7);

    float val = 0.f;
    if (lane < P * P) {
        const int i = lane / P;
        const int j = lane % P;
        // R1 boundary evaluation: mul-then-add, RN, no FMA; clip; cnt clipped.
        const float hs = fminf(fmaxf(floorf(__fadd_rn(y1, __fmul_rn(bin_h, (float)i))), 0.f), (float)FH);
        const float he = fminf(fmaxf(ceilf (__fadd_rn(y1, __fmul_rn(bin_h, (float)(i + 1)))), 0.f), (float)FH);
        const float wsb = fminf(fmaxf(floorf(__fadd_rn(x1, __fmul_rn(bin_w, (float)j))), 0.f), (float)FW);
        const float web = fminf(fmaxf(ceilf (__fadd_rn(x1, __fmul_rn(bin_w, (float)(j + 1)))), 0.f), (float)FW);
        const float cnt = __fmul_rn(__fsub_rn(he, hs), __fsub_rn(web, wsb));
        if (cnt > 0.f) {
            const int ys = (int)hs, ye = (int)he, xs = (int)wsb, xe = (int)web;
            const float* mp = maps + (size_t)(cbase + lane) * NPIX;
            float s = 0.f;
            for (int y = ys; y < ye; ++y)
                for (int x = xs; x < xe; ++x)
                    s += mp[y * FW + x];
            val = s / fmaxf(cnt, 1.0f);
        }
    }

    red[wid][lane] = val;
    __syncthreads();

    if (lane == 0) {
        float s = 0.f;
        for (int l = 0; l < P * P; ++l) s += red[wid][l];
        *outp = s * (1.0f / 49.0f);
    }
}

extern "C" void kernel_launch(void* const* d_in, const int* in_sizes, int n_in,
                              void* d_out, int out_size, void* d_ws, size_t ws_size,
                              hipStream_t stream) {
    const float* feature  = (const float*)d_in[0];   // [512, 38, 50]
    const float* rois     = (const float*)d_in[1];   // [300, 4]
    const float* w_double = (const float*)d_in[2];   // [1024, 512]
    const float* b_double = (const float*)d_in[3];   // [1024]
    const float* w_score  = (const float*)d_in[4];   // [1029, 1024]
    const float* b_score  = (const float*)d_in[5];   // [1029]
    const float* w_bbox   = (const float*)d_in[6];   // [4116, 1024]
    const float* b_bbox   = (const float*)d_in[7];   // [4116]
    float* out = (float*)d_out;                       // 6300 + 25200 floats

    const dim3 blk(256);
    const int nbx = (NPIX + 63) / 64;   // 30

    gemm1_k<<<dim3(nbx, (C_MID + 63) / 64), blk, 0, stream>>>(w_double, feature, b_double);
    gemm2_k<<<dim3(nbx, (C_CLS + 63) / 64), blk, 0, stream>>>(w_score, b_score);
    gemm3_k<<<dim3(nbx, (C_BOX + 63) / 64), blk, 0, stream>>>(w_bbox, b_bbox);

    psroi_pool_mean<<<dim3(NPAIRS / 4), blk, 0, stream>>>(rois, out);
}

// Round 15
// 240.357 us; speedup vs baseline: 1.8962x; 1.8962x over previous
//
#include <hip/hip_runtime.h>
#include <hip/hip_bf16.h>

// Problem constants
#define P 7
#define C_IN 512
#define C_MID 1024          // 2 * C_IN
#define C_CLS 1029          // P*P*21
#define C_BOX 4116          // P*P*21*4
#define FH 38
#define FW 50
#define NPIX 1900           // FH*FW
#define KROIS 300
#define COUT_SCORE 21
#define COUT_BOX 84
#define NPAIRS (KROIS * (COUT_SCORE + COUT_BOX))   // 31500

#define LDP 40   // LDS tile row pitch in bf16 units (80 B: 16B-aligned rows, 2-way-bank-free)

// Static device scratch. Fully overwritten every call; deterministic.
__device__ float g_featT [NPIX * C_IN];    // feature transposed: [1900][512]
__device__ float g_feat2T[NPIX * C_MID];   // feat2 transposed:   [1900][1024]
__device__ float g_score [C_CLS * NPIX];   // [1029][1900]
__device__ float g_bbox  [C_BOX * NPIX];   // [4116][1900]

typedef __attribute__((ext_vector_type(8))) short bf16x8;
typedef __attribute__((ext_vector_type(4))) float f32x4;

// f32 -> bf16 (RTNE) on raw bits; values are finite (no NaN handling needed).
__device__ __forceinline__ unsigned short f2b(float x) {
    unsigned u = __float_as_uint(x);
    unsigned r = u + 0x7fffu + ((u >> 16) & 1u);
    return (unsigned short)(r >> 16);
}
__device__ __forceinline__ float b2f(unsigned short h) {
    return __uint_as_float((unsigned)h << 16);
}

// Split 16 f32 (4 float4, k-contiguous) into hi/lo bf16 planes; write 2x uint4 each.
__device__ __forceinline__ void split16(const float4* v,
                                        unsigned short* dsth, unsigned short* dstl) {
    unsigned hu[8], lu[8];
    #pragma unroll
    for (int q = 0; q < 4; ++q) {
        const float a0 = v[q].x, a1 = v[q].y, a2 = v[q].z, a3 = v[q].w;
        const unsigned short h0 = f2b(a0), h1 = f2b(a1), h2 = f2b(a2), h3 = f2b(a3);
        const unsigned short l0 = f2b(a0 - b2f(h0)), l1 = f2b(a1 - b2f(h1));
        const unsigned short l2 = f2b(a2 - b2f(h2)), l3 = f2b(a3 - b2f(h3));
        hu[q * 2 + 0] = (unsigned)h0 | ((unsigned)h1 << 16);
        hu[q * 2 + 1] = (unsigned)h2 | ((unsigned)h3 << 16);
        lu[q * 2 + 0] = (unsigned)l0 | ((unsigned)l1 << 16);
        lu[q * 2 + 1] = (unsigned)l2 | ((unsigned)l3 << 16);
    }
    reinterpret_cast<uint4*>(dsth)[0] = make_uint4(hu[0], hu[1], hu[2], hu[3]);
    reinterpret_cast<uint4*>(dsth)[1] = make_uint4(hu[4], hu[5], hu[6], hu[7]);
    reinterpret_cast<uint4*>(dstl)[0] = make_uint4(lu[0], lu[1], lu[2], lu[3]);
    reinterpret_cast<uint4*>(dstl)[1] = make_uint4(lu[4], lu[5], lu[6], lu[7]);
}

// ---------------------------------------------------------------------------
// Transpose feature [512][1900] -> g_featT [1900][512]. 32x32 LDS tiles.
// ---------------------------------------------------------------------------
__global__ __launch_bounds__(256) void transpose_k(const float* __restrict__ in)
{
    __shared__ float t[32][33];
    const int n0 = blockIdx.x * 32;
    const int k0 = blockIdx.y * 32;
    const int tx = threadIdx.x & 31;
    const int ty = threadIdx.x >> 5;   // 0..7
    #pragma unroll
    for (int j = 0; j < 4; ++j) {
        const int kk = k0 + ty + j * 8;          // < 512 always (grid exact)
        const int nn = n0 + tx;
        t[ty + j * 8][tx] = (nn < NPIX) ? in[kk * NPIX + nn] : 0.f;
    }
    __syncthreads();
    #pragma unroll
    for (int j = 0; j < 4; ++j) {
        const int nn = n0 + ty + j * 8;
        const int kk = k0 + tx;
        if (nn < NPIX) g_featT[(size_t)nn * C_IN + kk] = t[tx][ty + j * 8];
    }
}

// ---------------------------------------------------------------------------
// Split-bf16 MFMA GEMM + bias + relu.
//   out[m,n] = relu( sum_k W[m,k] * X^T[n,k] + bias[m] )
// W row-major [M][K]; X passed TRANSPOSED [N][K] (k-contiguous rows) so both
// operands stage as [row][k] with k-contiguous b128 LDS writes AND reads.
// Precision: W = Wh+Wl, X = Xh+Xl (bf16 hi + bf16 residual, Sterbenz-exact);
//   acc += Ah*Bh + Ah*Bl + Al*Bh  (f32 accumulation; dropped Al*Bl ~ 2^-18).
// Tile 128x128, BK=32, 256 threads = 4 waves, each wave a 64x64 quadrant
// (4x4 fragments of mfma_f32_16x16x32_bf16).
// TROUT: store output TRANSPOSED as out[n*M + m] (float4 over 4 consecutive
// m from the C-fragment regs) — used by gemm1 to produce feat2T directly.
// ---------------------------------------------------------------------------
template <bool TROUT>
__global__ __launch_bounds__(256) void gemm_mfma(
    const float* __restrict__ W, const float* __restrict__ X,
    const float* __restrict__ bias, float* __restrict__ out,
    int M, int K, int N)
{
    __shared__ unsigned short sAh[128 * LDP], sAl[128 * LDP];
    __shared__ unsigned short sBh[128 * LDP], sBl[128 * LDP];

    const int tid = threadIdx.x;
    const int bm = blockIdx.y * 128;
    const int bn = blockIdx.x * 128;
    const int lane = tid & 63;
    const int wid = tid >> 6;
    const int wr = (wid >> 1) * 64;     // wave m-offset in tile
    const int wc = (wid & 1) * 64;      // wave n-offset in tile
    const int ll  = lane & 15;
    const int lh8 = (lane >> 4) * 8;
    const int lh4 = (lane >> 4) * 4;

    // staging map: thread t handles tile row t>>1, k-halfsegment (t&1)*16
    const int srow  = tid >> 1;          // 0..127
    const int skseg = (tid & 1) * 16;    // 0 or 16
    const int arow = bm + srow;          // global W row
    const int brow = bn + srow;          // global X^T row (= output col)

    f32x4 acc[4][4];
    #pragma unroll
    for (int i = 0; i < 4; ++i)
        #pragma unroll
        for (int j = 0; j < 4; ++j) {
            f32x4 z = {0.f, 0.f, 0.f, 0.f};
            acc[i][j] = z;
        }

    float4 wa[4], wb[4];
    const float4 f4z = make_float4(0.f, 0.f, 0.f, 0.f);

    // initial global loads (k0 = 0)
    {
        const float* pa = W + (size_t)arow * K + skseg;
        if (arow < M) { wa[0] = ((const float4*)pa)[0]; wa[1] = ((const float4*)pa)[1];
                        wa[2] = ((const float4*)pa)[2]; wa[3] = ((const float4*)pa)[3]; }
        else          { wa[0] = wa[1] = wa[2] = wa[3] = f4z; }
        const float* pb = X + (size_t)brow * K + skseg;
        if (brow < N) { wb[0] = ((const float4*)pb)[0]; wb[1] = ((const float4*)pb)[1];
                        wb[2] = ((const float4*)pb)[2]; wb[3] = ((const float4*)pb)[3]; }
        else          { wb[0] = wb[1] = wb[2] = wb[3] = f4z; }
    }

    for (int k0 = 0; k0 < K; k0 += 32) {
        // ---- stage current regs -> LDS (hi/lo planes) ----
        split16(wa, &sAh[srow * LDP + skseg], &sAl[srow * LDP + skseg]);
        split16(wb, &sBh[srow * LDP + skseg], &sBl[srow * LDP + skseg]);
        __syncthreads();

        // ---- prefetch next K-step (flies under the MFMAs below) ----
        const int kn = k0 + 32;
        if (kn < K) {
            const float* pa = W + (size_t)arow * K + kn + skseg;
            if (arow < M) { wa[0] = ((const float4*)pa)[0]; wa[1] = ((const float4*)pa)[1];
                            wa[2] = ((const float4*)pa)[2]; wa[3] = ((const float4*)pa)[3]; }
            const float* pb = X + (size_t)brow * K + kn + skseg;
            if (brow < N) { wb[0] = ((const float4*)pb)[0]; wb[1] = ((const float4*)pb)[1];
                            wb[2] = ((const float4*)pb)[2]; wb[3] = ((const float4*)pb)[3]; }
        }

        // ---- fragments + MFMA ----
        bf16x8 bhf[4], blf[4];
        #pragma unroll
        for (int nt = 0; nt < 4; ++nt) {
            const int r = wc + nt * 16 + ll;
            bhf[nt] = *reinterpret_cast<const bf16x8*>(&sBh[r * LDP + lh8]);
            blf[nt] = *reinterpret_cast<const bf16x8*>(&sBl[r * LDP + lh8]);
        }
        #pragma unroll
        for (int mt = 0; mt < 4; ++mt) {
            const int r = wr + mt * 16 + ll;
            const bf16x8 ahf = *reinterpret_cast<const bf16x8*>(&sAh[r * LDP + lh8]);
            const bf16x8 alf = *reinterpret_cast<const bf16x8*>(&sAl[r * LDP + lh8]);
            #pragma unroll
            for (int nt = 0; nt < 4; ++nt) {
                acc[mt][nt] = __builtin_amdgcn_mfma_f32_16x16x32_bf16(ahf, bhf[nt], acc[mt][nt], 0, 0, 0);
                acc[mt][nt] = __builtin_amdgcn_mfma_f32_16x16x32_bf16(ahf, blf[nt], acc[mt][nt], 0, 0, 0);
                acc[mt][nt] = __builtin_amdgcn_mfma_f32_16x16x32_bf16(alf, bhf[nt], acc[mt][nt], 0, 0, 0);
            }
        }
        __syncthreads();
    }

    // ---- epilogue: bias + relu ----
    // C/D layout (HW-verified): col = lane&15, row = (lane>>4)*4 + reg.
    #pragma unroll
    for (int mt = 0; mt < 4; ++mt) {
        #pragma unroll
        for (int nt = 0; nt < 4; ++nt) {
            const int m0 = bm + wr + mt * 16 + lh4;
            const int n  = bn + wc + nt * 16 + ll;
            if (TROUT) {
                if (n < N) {
                    float4 o;
                    o.x = fmaxf(acc[mt][nt][0] + bias[m0 + 0], 0.f);
                    o.y = fmaxf(acc[mt][nt][1] + bias[m0 + 1], 0.f);
                    o.z = fmaxf(acc[mt][nt][2] + bias[m0 + 2], 0.f);
                    o.w = fmaxf(acc[mt][nt][3] + bias[m0 + 3], 0.f);
                    *reinterpret_cast<float4*>(&out[(size_t)n * M + m0]) = o;
                }
            } else {
                #pragma unroll
                for (int r = 0; r < 4; ++r) {
                    const int m = m0 + r;
                    if (m < M && n < N)
                        out[(size_t)m * N + n] = fmaxf(acc[mt][nt][r] + bias[m], 0.f);
                }
            }
        }
    }
}

// ---------------------------------------------------------------------------
// PS-ROI pool + bin-mean — BYTE-IDENTICAL to the round-14 PASSING kernel.
// Verified oracle semantics: strict-f32 roi prep, bin_w via multiply-by-
// reciprocal (rn32(roi_w * rn32(1/7))), mul-then-add RN boundaries (no FMA),
// clipped cnt. DO NOT TOUCH.
// ---------------------------------------------------------------------------
__global__ __launch_bounds__(256) void psroi_pool_mean(
    const float* __restrict__ rois, float* __restrict__ out)
{
    __shared__ float red[4][64];
    const int wid = threadIdx.x >> 6;
    const int lane = threadIdx.x & 63;
    const int pair = blockIdx.x * 4 + wid;   // grid exact: pair < NPAIRS

    const int k = pair / (COUT_SCORE + COUT_BOX);
    const int c = pair % (COUT_SCORE + COUT_BOX);

    const float* maps;
    int cbase;
    float* outp;
    if (c < COUT_SCORE) {
        maps = g_score;
        cbase = c * (P * P);
        outp = out + (size_t)k * COUT_SCORE + c;
    } else {
        const int cb = c - COUT_SCORE;
        maps = g_bbox;
        cbase = cb * (P * P);
        outp = out + (size_t)KROIS * COUT_SCORE + (size_t)k * COUT_BOX + cb;
    }

    // rois layout: (ymin, xmin, ymax, xmax); reference permutes to xyxy.
    const float ymin = rois[k * 4 + 0];
    const float xmin = rois[k * 4 + 1];
    const float ymax = rois[k * 4 + 2];
    const float xmax = rois[k * 4 + 3];

    const float x1 = __fmul_rn(rintf(xmin), 0.0625f);
    const float y1 = __fmul_rn(rintf(ymin), 0.0625f);
    const float x2 = __fmul_rn(__fadd_rn(rintf(xmax), 1.0f), 0.0625f);
    const float y2 = __fmul_rn(__fadd_rn(rintf(ymax), 1.0f), 0.0625f);
    const float roi_w = fmaxf(__fsub_rn(x2, x1), 0.1f);
    const float roi_h = fmaxf(__fsub_rn(y2, y1), 0.1f);
    const float inv7 = 1.0f / 7.0f;   // constant-folded rn32(1/7)
    const float bin_w = __fmul_rn(roi_w, inv7);
    const float bin_h = __fmul_rn(roi_h, inv7);

    float val = 0.f;
    if (lane < P * P) {
        const int i = lane / P;
        const int j = lane % P;
        const float hs = fminf(fmaxf(floorf(__fadd_rn(y1, __fmul_rn(bin_h, (float)i))), 0.f), (float)FH);
        const float he = fminf(fmaxf(ceilf (__fadd_rn(y1, __fmul_rn(bin_h, (float)(i + 1)))), 0.f), (float)FH);
        const float wsb = fminf(fmaxf(floorf(__fadd_rn(x1, __fmul_rn(bin_w, (float)j))), 0.f), (float)FW);
        const float web = fminf(fmaxf(ceilf (__fadd_rn(x1, __fmul_rn(bin_w, (float)(j + 1)))), 0.f), (float)FW);
        const float cnt = __fmul_rn(__fsub_rn(he, hs), __fsub_rn(web, wsb));
        if (cnt > 0.f) {
            const int ys = (int)hs, ye = (int)he, xs = (int)wsb, xe = (int)web;
            const float* mp = maps + (size_t)(cbase + lane) * NPIX;
            float s = 0.f;
            for (int y = ys; y < ye; ++y)
                for (int x = xs; x < xe; ++x)
                    s += mp[y * FW + x];
            val = s / fmaxf(cnt, 1.0f);
        }
    }

    red[wid][lane] = val;
    __syncthreads();

    if (lane == 0) {
        float s = 0.f;
        for (int l = 0; l < P * P; ++l) s += red[wid][l];
        *outp = s * (1.0f / 49.0f);
    }
}

extern "C" void kernel_launch(void* const* d_in, const int* in_sizes, int n_in,
                              void* d_out, int out_size, void* d_ws, size_t ws_size,
                              hipStream_t stream) {
    const float* feature  = (const float*)d_in[0];   // [512, 38, 50]
    const float* rois     = (const float*)d_in[1];   // [300, 4]
    const float* w_double = (const float*)d_in[2];   // [1024, 512]
    const float* b_double = (const float*)d_in[3];   // [1024]
    const float* w_score  = (const float*)d_in[4];   // [1029, 1024]
    const float* b_score  = (const float*)d_in[5];   // [1029]
    const float* w_bbox   = (const float*)d_in[6];   // [4116, 1024]
    const float* b_bbox   = (const float*)d_in[7];   // [4116]
    float* out = (float*)d_out;                       // 6300 + 25200 floats

    float* featT  = nullptr; hipGetSymbolAddress((void**)&featT,  HIP_SYMBOL(g_featT));
    float* feat2T = nullptr; hipGetSymbolAddress((void**)&feat2T, HIP_SYMBOL(g_feat2T));
    float* scoreM = nullptr; hipGetSymbolAddress((void**)&scoreM, HIP_SYMBOL(g_score));
    float* bboxM  = nullptr; hipGetSymbolAddress((void**)&bboxM,  HIP_SYMBOL(g_bbox));

    const dim3 blk(256);

    // feature [512][1900] -> featT [1900][512]
    transpose_k<<<dim3((NPIX + 31) / 32, C_IN / 32), blk, 0, stream>>>(feature);

    // gemm1: feat2T[n][m] = relu(W1 . featT^T), output TRANSPOSED
    gemm_mfma<true ><<<dim3((NPIX + 127) / 128, (C_MID + 127) / 128), blk, 0, stream>>>(
        w_double, featT, b_double, feat2T, C_MID, C_IN, NPIX);

    // gemm2/3: natural [M][N] outputs for pooling
    gemm_mfma<false><<<dim3((NPIX + 127) / 128, (C_CLS + 127) / 128), blk, 0, stream>>>(
        w_score, feat2T, b_score, scoreM, C_CLS, C_MID, NPIX);
    gemm_mfma<false><<<dim3((NPIX + 127) / 128, (C_BOX + 127) / 128), blk, 0, stream>>>(
        w_bbox, feat2T, b_bbox, bboxM, C_BOX, C_MID, NPIX);

    psroi_pool_mean<<<dim3(NPAIRS / 4), blk, 0, stream>>>(rois, out);
}

// Round 16
// 218.356 us; speedup vs baseline: 2.0872x; 1.1008x over previous
//
#include <hip/hip_runtime.h>
#include <hip/hip_bf16.h>

// Problem constants
#define P 7
#define C_IN 512
#define C_MID 1024          // 2 * C_IN
#define C_CLS 1029          // P*P*21
#define C_BOX 4116          // P*P*21*4
#define FH 38
#define FW 50
#define NPIX 1900           // FH*FW
#define KROIS 300
#define COUT_SCORE 21
#define COUT_BOX 84
#define NPAIRS (KROIS * (COUT_SCORE + COUT_BOX))   // 31500

// Padded GEMM dims (multiples of 128)
#define MP1 1024
#define MP2 1152
#define MP3 4224
#define NPAD 1920

// Static device scratch. Fully overwritten every call; deterministic.
__device__ unsigned short g_w1h[MP1 * C_IN],  g_w1l[MP1 * C_IN];    // w_double planes
__device__ unsigned short g_w2h[MP2 * C_MID], g_w2l[MP2 * C_MID];   // w_score planes
__device__ unsigned short g_w3h[MP3 * C_MID], g_w3l[MP3 * C_MID];   // w_bbox planes
__device__ unsigned short g_fTh[NPAD * C_IN], g_fTl[NPAD * C_IN];   // feature^T planes
__device__ unsigned short g_f2Th[NPAD * C_MID], g_f2Tl[NPAD * C_MID]; // feat2^T planes
__device__ float g_score[C_CLS * NPIX];   // [1029][1900] f32
__device__ float g_bbox [C_BOX * NPIX];   // [4116][1900] f32

typedef __attribute__((ext_vector_type(8))) short bf16x8;
typedef __attribute__((ext_vector_type(4))) float f32x4;

// f32 -> bf16 (RTNE) on raw bits; values finite.
__device__ __forceinline__ unsigned short f2b(float x) {
    unsigned u = __float_as_uint(x);
    unsigned r = u + 0x7fffu + ((u >> 16) & 1u);
    return (unsigned short)(r >> 16);
}
__device__ __forceinline__ float b2f(unsigned short h) {
    return __uint_as_float((unsigned)h << 16);
}

// async global->LDS, 16B per lane. LDS dest = uniform base + lane*16 (HW).
#define GLOAD16(gp, lp)                                                        \
    __builtin_amdgcn_global_load_lds(                                          \
        (const __attribute__((address_space(1))) void*)(gp),                   \
        (__attribute__((address_space(3))) void*)(lp), 16, 0, 0)

// ---------------------------------------------------------------------------
// Split f32 array into bf16 hi/lo planes, zero-padding tail rows.
// Operates on float4 granules: i < n_in4 -> split(src), else zeros.
// ---------------------------------------------------------------------------
__global__ __launch_bounds__(256) void split_pad_k(
    const float* __restrict__ src,
    unsigned short* __restrict__ h, unsigned short* __restrict__ l,
    int n_in4, int n_pad4)
{
    const int i = blockIdx.x * 256 + threadIdx.x;
    if (i >= n_pad4) return;
    float4 v = make_float4(0.f, 0.f, 0.f, 0.f);
    if (i < n_in4) v = reinterpret_cast<const float4*>(src)[i];
    ushort4 hh, lv;
    hh.x = f2b(v.x); lv.x = f2b(v.x - b2f(hh.x));
    hh.y = f2b(v.y); lv.y = f2b(v.y - b2f(hh.y));
    hh.z = f2b(v.z); lv.z = f2b(v.z - b2f(hh.z));
    hh.w = f2b(v.w); lv.w = f2b(v.w - b2f(hh.w));
    reinterpret_cast<ushort4*>(h)[i] = hh;
    reinterpret_cast<ushort4*>(l)[i] = lv;
}

// ---------------------------------------------------------------------------
// Transpose feature [512][1900] -> g_fTh/g_fTl bf16 [1920][512] (pad rows 0).
// ---------------------------------------------------------------------------
__global__ __launch_bounds__(256) void transpose_split_k(const float* __restrict__ in)
{
    __shared__ float t[32][33];
    const int n0 = blockIdx.x * 32;    // pixel (60 blocks -> 1920)
    const int k0 = blockIdx.y * 32;    // channel (16 blocks -> 512)
    const int tx = threadIdx.x & 31;
    const int ty = threadIdx.x >> 5;   // 0..7
    #pragma unroll
    for (int j = 0; j < 4; ++j) {
        const int kk = k0 + ty + j * 8;
        const int nn = n0 + tx;
        t[ty + j * 8][tx] = (nn < NPIX) ? in[kk * NPIX + nn] : 0.f;
    }
    __syncthreads();
    #pragma unroll
    for (int j = 0; j < 4; ++j) {
        const int nn = n0 + ty + j * 8;
        const int kk = k0 + tx;
        const float v = t[tx][ty + j * 8];
        const unsigned short hh = f2b(v);
        g_fTh[(size_t)nn * C_IN + kk] = hh;
        g_fTl[(size_t)nn * C_IN + kk] = f2b(v - b2f(hh));
    }
}

// ---------------------------------------------------------------------------
// Split-bf16 MFMA GEMM + bias + relu, pre-split operands, gload_lds staging.
//   out[m,n] = relu( sum_k (Ah+Al)[m,k] * (Bh+Bl)[n,k] + bias[m] )
// acc += Ah*Bh + Ah*Bl + Al*Bh (f32 accum; Al*Bl ~2^-18 dropped) — identical
// numerics to the passing R15 kernel (pre-split is bit-identical).
//
// Tile 128x128, BK=64, 4 waves (64x64 each). LDS: 4 planes x 128 rows x 128B
// = 64 KB, single-buffered. XOR swizzle: k-seg s of row r stored at slot
// s^(r&7) (16B slots). Staged via global_load_lds with pre-swizzled GLOBAL
// source (linear LDS dest, per-lane global addr — rule-21-correct), read
// with the same XOR -> 64 lanes hit 8 bank-quads uniformly (conflict-free).
// TROUT: epilogue emits transposed bf16 hi/lo planes (for feat2T).
// ---------------------------------------------------------------------------
template <bool TROUT>
__global__ __launch_bounds__(256) void gemm_mfma(
    const unsigned short* __restrict__ Ah, const unsigned short* __restrict__ Al,
    const unsigned short* __restrict__ Bh, const unsigned short* __restrict__ Bl,
    const float* __restrict__ bias,
    float* __restrict__ out,                       // non-TROUT
    unsigned short* __restrict__ outh,             // TROUT
    unsigned short* __restrict__ outl,             // TROUT
    int M, int K, int N)
{
    __shared__ unsigned char lds[65536];   // planes: Ah,Al,Bh,Bl @ 16KB each

    const int tid = threadIdx.x;
    const int bm = blockIdx.y * 128;
    const int bn = blockIdx.x * 128;
    const int lane = tid & 63;
    const int wid = tid >> 6;
    const int uwid = __builtin_amdgcn_readfirstlane(wid);
    const int wr = (wid >> 1) * 64;
    const int wc = (wid & 1) * 64;
    const int ll = lane & 15;
    const int lg = lane >> 4;        // 0..3
    const int lh4 = lg * 4;

    // staging: wave uwid stages plane uwid (0=Ah 1=Al 2=Bh 3=Bl).
    // per instr g: 8 rows x 128B. lane -> row g*8 + (lane>>3), dest slot lane&7.
    // source k-seg for dest slot d at row r: d ^ (r&7)  (r&7 == lane>>3 here).
    const int lrow = lane >> 3;                 // 0..7
    const int lseg = (lane & 7) ^ lrow;         // pre-swizzled source k-seg
    const unsigned short* gsrc = (uwid == 0) ? Ah : (uwid == 1) ? Al : (uwid == 2) ? Bh : Bl;
    const int rbase = (uwid < 2) ? bm : bn;
    unsigned char* lplane = &lds[uwid * 16384];

    f32x4 acc[4][4];
    #pragma unroll
    for (int i = 0; i < 4; ++i)
        #pragma unroll
        for (int j = 0; j < 4; ++j) {
            f32x4 z = {0.f, 0.f, 0.f, 0.f};
            acc[i][j] = z;
        }

    const unsigned char* pAh = &lds[0];
    const unsigned char* pAl = &lds[16384];
    const unsigned char* pBh = &lds[32768];
    const unsigned char* pBl = &lds[49152];

    for (int k0 = 0; k0 < K; k0 += 64) {
        // ---- stage this K-step (each wave its plane; 16 x 1KB) ----
        const unsigned short* gp = gsrc + (size_t)(rbase + lrow) * K + lseg * 8 + k0;
        #pragma unroll
        for (int g = 0; g < 16; ++g)
            GLOAD16(gp + (size_t)g * 8 * K, lplane + g * 1024);
        asm volatile("s_waitcnt vmcnt(0)" ::: "memory");
        __syncthreads();

        // ---- fragments + MFMA (swizzled reads) ----
        #pragma unroll
        for (int kh = 0; kh < 2; ++kh) {
            const int slot = kh * 4 + lg;
            bf16x8 bh[4], bl[4];
            #pragma unroll
            for (int nt = 0; nt < 4; ++nt) {
                const int r = wc + nt * 16 + ll;
                const int so = ((slot ^ (r & 7)) << 4);
                bh[nt] = *reinterpret_cast<const bf16x8*>(pBh + r * 128 + so);
                bl[nt] = *reinterpret_cast<const bf16x8*>(pBl + r * 128 + so);
            }
            #pragma unroll
            for (int mt = 0; mt < 4; ++mt) {
                const int r = wr + mt * 16 + ll;
                const int so = ((slot ^ (r & 7)) << 4);
                const bf16x8 ah = *reinterpret_cast<const bf16x8*>(pAh + r * 128 + so);
                const bf16x8 al = *reinterpret_cast<const bf16x8*>(pAl + r * 128 + so);
                #pragma unroll
                for (int nt = 0; nt < 4; ++nt) {
                    acc[mt][nt] = __builtin_amdgcn_mfma_f32_16x16x32_bf16(ah, bh[nt], acc[mt][nt], 0, 0, 0);
                    acc[mt][nt] = __builtin_amdgcn_mfma_f32_16x16x32_bf16(ah, bl[nt], acc[mt][nt], 0, 0, 0);
                    acc[mt][nt] = __builtin_amdgcn_mfma_f32_16x16x32_bf16(al, bh[nt], acc[mt][nt], 0, 0, 0);
                }
            }
        }
        __syncthreads();
    }

    // ---- epilogue: bias + relu. C/D: col = lane&15, row = (lane>>4)*4+reg ----
    #pragma unroll
    for (int mt = 0; mt < 4; ++mt) {
        #pragma unroll
        for (int nt = 0; nt < 4; ++nt) {
            const int m0 = bm + wr + mt * 16 + lh4;
            const int n  = bn + wc + nt * 16 + ll;
            if (TROUT) {
                // grid is exact (n < NPAD); write all rows incl. pad (deterministic).
                float o0 = fmaxf(acc[mt][nt][0] + bias[m0 + 0], 0.f);
                float o1 = fmaxf(acc[mt][nt][1] + bias[m0 + 1], 0.f);
                float o2 = fmaxf(acc[mt][nt][2] + bias[m0 + 2], 0.f);
                float o3 = fmaxf(acc[mt][nt][3] + bias[m0 + 3], 0.f);
                ushort4 hh, lv;
                hh.x = f2b(o0); lv.x = f2b(o0 - b2f(hh.x));
                hh.y = f2b(o1); lv.y = f2b(o1 - b2f(hh.y));
                hh.z = f2b(o2); lv.z = f2b(o2 - b2f(hh.z));
                hh.w = f2b(o3); lv.w = f2b(o3 - b2f(hh.w));
                *reinterpret_cast<ushort4*>(&outh[(size_t)n * M + m0]) = hh;
                *reinterpret_cast<ushort4*>(&outl[(size_t)n * M + m0]) = lv;
            } else {
                #pragma unroll
                for (int r = 0; r < 4; ++r) {
                    const int m = m0 + r;
                    if (m < M && n < N)
                        out[(size_t)m * N + n] = fmaxf(acc[mt][nt][r] + bias[m], 0.f);
                }
            }
        }
    }
}

// ---------------------------------------------------------------------------
// PS-ROI pool + bin-mean. SEMANTICS LOCKED (R14-verified oracle match):
// strict-f32 roi prep, bin via rn32(roi * rn32(1/7)), mul-then-add RN
// boundaries, clipped cnt. Only change vs R15: the inner gather uses a
// 16-way predicated unroll when the window fits 4x4 (all unclipped rois);
// term sequence and f32 add order are IDENTICAL (skipped slots add +0.0,
// exact on the non-negative relu'd sums).
// ---------------------------------------------------------------------------
__global__ __launch_bounds__(256) void psroi_pool_mean(
    const float* __restrict__ rois, float* __restrict__ out)
{
    __shared__ float red[4][64];
    const int wid = threadIdx.x >> 6;
    const int lane = threadIdx.x & 63;
    const int pair = blockIdx.x * 4 + wid;   // grid exact: pair < NPAIRS

    const int k = pair / (COUT_SCORE + COUT_BOX);
    const int c = pair % (COUT_SCORE + COUT_BOX);

    const float* maps;
    int cbase;
    float* outp;
    if (c < COUT_SCORE) {
        maps = g_score;
        cbase = c * (P * P);
        outp = out + (size_t)k * COUT_SCORE + c;
    } else {
        const int cb = c - COUT_SCORE;
        maps = g_bbox;
        cbase = cb * (P * P);
        outp = out + (size_t)KROIS * COUT_SCORE + (size_t)k * COUT_BOX + cb;
    }

    // rois layout: (ymin, xmin, ymax, xmax); reference permutes to xyxy.
    const float ymin = rois[k * 4 + 0];
    const float xmin = rois[k * 4 + 1];
    const float ymax = rois[k * 4 + 2];
    const float xmax = rois[k * 4 + 3];

    const float x1 = __fmul_rn(rintf(xmin), 0.0625f);
    const float y1 = __fmul_rn(rintf(ymin), 0.0625f);
    const float x2 = __fmul_rn(__fadd_rn(rintf(xmax), 1.0f), 0.0625f);
    const float y2 = __fmul_rn(__fadd_rn(rintf(ymax), 1.0f), 0.0625f);
    const float roi_w = fmaxf(__fsub_rn(x2, x1), 0.1f);
    const float roi_h = fmaxf(__fsub_rn(y2, y1), 0.1f);
    const float inv7 = 1.0f / 7.0f;   // constant-folded rn32(1/7)
    const float bin_w = __fmul_rn(roi_w, inv7);
    const float bin_h = __fmul_rn(roi_h, inv7);

    float val = 0.f;
    if (lane < P * P) {
        const int i = lane / P;
        const int j = lane % P;
        const float hs = fminf(fmaxf(floorf(__fadd_rn(y1, __fmul_rn(bin_h, (float)i))), 0.f), (float)FH);
        const float he = fminf(fmaxf(ceilf (__fadd_rn(y1, __fmul_rn(bin_h, (float)(i + 1)))), 0.f), (float)FH);
        const float wsb = fminf(fmaxf(floorf(__fadd_rn(x1, __fmul_rn(bin_w, (float)j))), 0.f), (float)FW);
        const float web = fminf(fmaxf(ceilf (__fadd_rn(x1, __fmul_rn(bin_w, (float)(j + 1)))), 0.f), (float)FW);
        const float cnt = __fmul_rn(__fsub_rn(he, hs), __fsub_rn(web, wsb));
        if (cnt > 0.f) {
            const int ys = (int)hs, ye = (int)he, xs = (int)wsb, xe = (int)web;
            const int rows = ye - ys, cols = xe - xs;
            const float* mp = maps + (size_t)(cbase + lane) * NPIX;
            float s = 0.f;
            if (rows <= 4 && cols <= 4) {
                #pragma unroll
                for (int t = 0; t < 16; ++t) {
                    const int dy = t >> 2, dx = t & 3;
                    const float v = (dy < rows && dx < cols)
                                        ? mp[(ys + dy) * FW + (xs + dx)] : 0.f;
                    s += v;
                }
            } else {
                for (int y = ys; y < ye; ++y)
                    for (int x = xs; x < xe; ++x)
                        s += mp[y * FW + x];
            }
            val = s / fmaxf(cnt, 1.0f);
        }
    }

    red[wid][lane] = val;
    __syncthreads();

    if (lane == 0) {
        float s = 0.f;
        for (int l = 0; l < P * P; ++l) s += red[wid][l];
        *outp = s * (1.0f / 49.0f);
    }
}

extern "C" void kernel_launch(void* const* d_in, const int* in_sizes, int n_in,
                              void* d_out, int out_size, void* d_ws, size_t ws_size,
                              hipStream_t stream) {
    const float* feature  = (const float*)d_in[0];   // [512, 38, 50]
    const float* rois     = (const float*)d_in[1];   // [300, 4]
    const float* w_double = (const float*)d_in[2];   // [1024, 512]
    const float* b_double = (const float*)d_in[3];   // [1024]
    const float* w_score  = (const float*)d_in[4];   // [1029, 1024]
    const float* b_score  = (const float*)d_in[5];   // [1029]
    const float* w_bbox   = (const float*)d_in[6];   // [4116, 1024]
    const float* b_bbox   = (const float*)d_in[7];   // [4116]
    float* out = (float*)d_out;                       // 6300 + 25200 floats

    unsigned short *w1h, *w1l, *w2h, *w2l, *w3h, *w3l, *fTh, *fTl, *f2Th, *f2Tl;
    float *scoreM, *bboxM;
    hipGetSymbolAddress((void**)&w1h,  HIP_SYMBOL(g_w1h));
    hipGetSymbolAddress((void**)&w1l,  HIP_SYMBOL(g_w1l));
    hipGetSymbolAddress((void**)&w2h,  HIP_SYMBOL(g_w2h));
    hipGetSymbolAddress((void**)&w2l,  HIP_SYMBOL(g_w2l));
    hipGetSymbolAddress((void**)&w3h,  HIP_SYMBOL(g_w3h));
    hipGetSymbolAddress((void**)&w3l,  HIP_SYMBOL(g_w3l));
    hipGetSymbolAddress((void**)&fTh,  HIP_SYMBOL(g_fTh));
    hipGetSymbolAddress((void**)&fTl,  HIP_SYMBOL(g_fTl));
    hipGetSymbolAddress((void**)&f2Th, HIP_SYMBOL(g_f2Th));
    hipGetSymbolAddress((void**)&f2Tl, HIP_SYMBOL(g_f2Tl));
    hipGetSymbolAddress((void**)&scoreM, HIP_SYMBOL(g_score));
    hipGetSymbolAddress((void**)&bboxM,  HIP_SYMBOL(g_bbox));

    const dim3 blk(256);

    // split weights into bf16 hi/lo planes (zero-padded rows)
    split_pad_k<<<(MP1 * C_IN / 4 + 255) / 256, blk, 0, stream>>>(
        w_double, w1h, w1l, C_MID * C_IN / 4, MP1 * C_IN / 4);
    split_pad_k<<<(MP2 * C_MID / 4 + 255) / 256, blk, 0, stream>>>(
        w_score, w2h, w2l, C_CLS * C_MID / 4, MP2 * C_MID / 4);
    split_pad_k<<<(MP3 * C_MID / 4 + 255) / 256, blk, 0, stream>>>(
        w_bbox, w3h, w3l, C_BOX * C_MID / 4, MP3 * C_MID / 4);

    // feature [512][1900] -> fT hi/lo [1920][512]
    transpose_split_k<<<dim3(NPAD / 32, C_IN / 32), blk, 0, stream>>>(feature);

    // gemm1: feat2T hi/lo (transposed epilogue)
    gemm_mfma<true ><<<dim3(NPAD / 128, MP1 / 128), blk, 0, stream>>>(
        w1h, w1l, fTh, fTl, b_double, nullptr, f2Th, f2Tl, C_MID, C_IN, NPIX);

    // gemm2/3: natural [M][N] f32 outputs for pooling
    gemm_mfma<false><<<dim3(NPAD / 128, MP2 / 128), blk, 0, stream>>>(
        w2h, w2l, f2Th, f2Tl, b_score, scoreM, nullptr, nullptr, C_CLS, C_MID, NPIX);
    gemm_mfma<false><<<dim3(NPAD / 128, MP3 / 128), blk, 0, stream>>>(
        w3h, w3l, f2Th, f2Tl, b_bbox, bboxM, nullptr, nullptr, C_BOX, C_MID, NPIX);

    psroi_pool_mean<<<dim3(NPAIRS / 4), blk, 0, stream>>>(rois, out);
}